// Round 1
// baseline (131.675 us; speedup 1.0000x reference)
//
#include <hip/hip_runtime.h>

#define HH 256
#define WW 256
#define KK 4
#define TILE 16
#define HALO 18               // 16 + 1-pixel halo each side
#define NPIX (HALO*HALO)      // 324
#define NITEM (NPIX*KK)       // 1296
#define BIGF 1e10f
#define NORM_C 0.6503144f     // 1.05 / (1 + 4e^-2 + 4e^-4)

__global__ __launch_bounds__(256) void splat_phong(
    const float* __restrict__ texels,
    const float* __restrict__ normals,
    const float* __restrict__ pccam,
    const float* __restrict__ pcscr,
    const float* __restrict__ qdep,
    const int*   __restrict__ bgmask,
    const float* __restrict__ lpos,
    const float* __restrict__ lamb,
    const float* __restrict__ ldif,
    const float* __restrict__ lspec,
    const float* __restrict__ campos,
    const float* __restrict__ mamb,
    const float* __restrict__ mdif,
    const float* __restrict__ mspec,
    float* __restrict__ out)
{
    // k-plane SoA: phase-2 reads are unit-stride (16B/lane) across tx -> conflict-free
    __shared__ float4 s_cjy[NITEM];   // [k][pi] : rgb + jy (jy=BIG when alpha==0 or OOB)
    __shared__ float  s_jx [NITEM];   // [k][pi]
    __shared__ float4 s_d4 [NPIX];    // [pi]    : depths (k0..k3) packed, one b128 per gather

    // XCD-aware bijective swizzle: gridDim.x = 256*N, divisible by 8.
    // Consecutive original bids round-robin over the 8 XCDs; remap so each XCD
    // owns a contiguous chunk of tiles (8 tile-rows) -> halo overlap hits its L2.
    int bid = (int)blockIdx.x;
    const int cpx = (int)gridDim.x >> 3;
    bid = (bid & 7) * cpx + (bid >> 3);
    const int n    = bid >> 8;            // 256 tiles per image
    const int tile = bid & 255;
    const int y0 = (tile >> 4) * TILE;
    const int x0 = (tile & 15) * TILE;
    const int tid = (int)threadIdx.x;

    // uniform small vectors (L2-resident; compiler scalarizes)
    const float lx0 = lpos[0],  ly0 = lpos[1],  lz0 = lpos[2];
    const float cx0 = campos[0], cy0 = campos[1], cz0 = campos[2];
    const float A0 = lamb[0]*mamb[0],  A1 = lamb[1]*mamb[1],  A2 = lamb[2]*mamb[2];
    const float D0 = ldif[0]*mdif[0],  D1 = ldif[1]*mdif[1],  D2 = ldif[2]*mdif[2];
    const float S0 = lspec[0]*mspec[0], S1 = lspec[1]*mspec[1], S2 = lspec[2]*mspec[2];

    // ---- Phase 1: shade the 18x18x4 halo into LDS (each item shaded ONCE) ----
    for (int it = tid; it < NITEM; it += 256) {
        const int k  = it & (KK-1);
        const int pi = it >> 2;
        const int hy = pi / HALO;
        const int hx = pi - hy*HALO;
        const int y = y0 - 1 + hy;
        const int x = x0 - 1 + hx;
        float4 cjy = make_float4(0.f, 0.f, 0.f, BIGF);  // rgb=0, jy=BIG -> zero weight
        float jx = 0.f, dep = BIGF;
        if ((unsigned)y < HH && (unsigned)x < WW) {
            const int base = ((n*HH + y)*WW + x)*KK + k;
            const float* nr = normals + (size_t)base*3;
            float nx = nr[0], ny = nr[1], nz = nr[2];
            float ri = rsqrtf(nx*nx + ny*ny + nz*nz + 1e-8f);
            nx *= ri; ny *= ri; nz *= ri;
            const float* pc = pccam + (size_t)base*3;
            const float px = pc[0], py = pc[1], pz = pc[2];
            float llx = lx0-px, lly = ly0-py, llz = lz0-pz;
            ri = rsqrtf(llx*llx + lly*lly + llz*llz + 1e-8f);
            llx *= ri; lly *= ri; llz *= ri;
            float vx = cx0-px, vy = cy0-py, vz = cz0-pz;
            ri = rsqrtf(vx*vx + vy*vy + vz*vz + 1e-8f);
            vx *= ri; vy *= ri; vz *= ri;
            const float ndl = nx*llx + ny*lly + nz*llz;
            const float rx = 2.f*ndl*nx - llx;
            const float ry = 2.f*ndl*ny - lly;
            const float rz = 2.f*ndl*nz - llz;
            float rdv = fmaxf(rx*vx + ry*vy + rz*vz, 0.f);
            const float p2 = rdv*rdv, p4 = p2*p2, p8 = p4*p4;
            const float p16 = p8*p8, p32 = p16*p16, p64 = p32*p32;
            const float ndlr = fmaxf(ndl, 0.f);
            const float* t3 = texels + (size_t)base*3;
            cjy.x = t3[0]*(A0 + D0*ndlr) + S0*p64;
            cjy.y = t3[1]*(A1 + D1*ndlr) + S1*p64;
            cjy.z = t3[2]*(A2 + D2*ndlr) + S2*p64;
            const float2 j2 = *reinterpret_cast<const float2*>(pcscr + (size_t)base*2);
            // alpha folded into jy: bgmask -> jy=BIG -> expf(-huge)=0 exactly
            cjy.w = bgmask[base] ? BIGF : (j2.x - ((float)y + 0.5f));
            jx  = j2.y - ((float)x + 0.5f);
            dep = qdep[base];                    // OOB stays BIG (matches _shift pad)
        }
        s_cjy[k*NPIX + pi] = cjy;
        s_jx [k*NPIX + pi] = jx;
        reinterpret_cast<float*>(s_d4)[pi*4 + k] = dep;
    }
    __syncthreads();

    // ---- Phase 2: one thread per output pixel, gather 9 neighbors x 4 layers ----
    const int ty = tid >> 4;
    const int tx = tid & 15;
    const float4 q = s_d4[(ty+1)*HALO + (tx+1)];

    // 3 classes x (rgb + wsum). Note: reference's splat alpha-channel == its
    // w-channel exactly (alpha in {0,1} and w already carries the alpha factor),
    // so one accumulator serves both.
    float fr=0.f, fg=0.f, fb=0.f, fw=0.f;
    float sr=0.f, sg=0.f, sb=0.f, sw=0.f;
    float br=0.f, bg=0.f, bb=0.f, bw=0.f;

    #pragma unroll
    for (int d = 0; d < 9; ++d) {
        const int dyy = d/3 - 1;
        const int dxx = d - (d/3)*3 - 1;
        const int pi = (ty+1-dyy)*HALO + (tx+1-dxx);   // neighbor p = gather - (dy,dx)
        const float4 pd = s_d4[pi];                    // one conflict-free b128
        // lq = argmin_k |p_top - q_k| (first-min, strict <), dq_min
        const float t0 = fabsf(pd.x - q.x);
        float t;
        float dqm = t0; int lq = 0;
        t = fabsf(pd.x - q.y); if (t < dqm) { dqm = t; lq = 1; }
        t = fabsf(pd.x - q.z); if (t < dqm) { dqm = t; lq = 2; }
        t = fabsf(pd.x - q.w); if (t < dqm) { dqm = t; lq = 3; }
        // lp = argmin_k |q_top - p_k|, dp_min
        float dpm = t0; int lp = 0;
        t = fabsf(q.x - pd.y); if (t < dpm) { dpm = t; lp = 1; }
        t = fabsf(q.x - pd.z); if (t < dpm) { dpm = t; lp = 2; }
        t = fabsf(q.x - pd.w); if (t < dpm) { dpm = t; lp = 3; }
        const int occ = (dqm <= dpm) ? lq : -lp;
        const float fdy = (float)dyy, fdx = (float)dxx;
        #pragma unroll
        for (int k = 0; k < KK; ++k) {
            const float4 r  = s_cjy[k*NPIX + pi];      // rgb + jy, conflict-free b128
            const float pjx = s_jx [k*NPIX + pi];      // conflict-free b32
            const float ddy = r.w - fdy;
            const float ddx = pjx - fdx;
            // exp(-dist2/(2*sigma^2)) with 2*sigma^2 = 0.5 -> exp(-2*dist2);
            // alpha==0 items have ddy ~ 1e10 -> weight exactly 0
            const float wgt = __expf(-2.0f*(ddy*ddy + ddx*ddx)) * NORM_C;
            const int level = k + occ;
            const float wf = (level <  0) ? wgt : 0.f;
            const float ws = (level == 0) ? wgt : 0.f;
            const float wb = (level >  0) ? wgt : 0.f;
            fr += r.x*wf; fg += r.y*wf; fb += r.z*wf; fw += wf;
            sr += r.x*ws; sg += r.y*ws; sb += r.z*ws; sw += ws;
            br += r.x*wb; bg += r.y*wb; bb += r.z*wb; bw += wb;
        }
    }

    // normalize each class, composite bg <- surf <- fg, then over background color
    const float ifg = 1.f / fmaxf(fw, 1e-10f);
    const float isf = 1.f / fmaxf(sw, 1e-10f);
    const float ibg = 1.f / fmaxf(bw, 1e-10f);
    float o0 = br*ibg, o1 = bg*ibg, o2 = bb*ibg, o3 = bw*ibg;
    const float sa = sw*isf;
    o0 = sr*isf + (1.f - sa)*o0;
    o1 = sg*isf + (1.f - sa)*o1;
    o2 = sb*isf + (1.f - sa)*o2;
    o3 = sa     + (1.f - sa)*o3;
    const float fa = fw*ifg;
    o0 = fr*ifg + (1.f - fa)*o0;
    o1 = fg*ifg + (1.f - fa)*o1;
    o2 = fb*ifg + (1.f - fa)*o2;
    o3 = fa     + (1.f - fa)*o3;
    const float bgc = 1.f - o3;   // BG_COLOR = (1,1,1)
    const float4 res = make_float4(o0 + bgc, o1 + bgc, o2 + bgc, o3);

    const int y = y0 + ty, x = x0 + tx;
    float4* op = (float4*)(out + (size_t)((n*HH + y)*WW + x)*4);
    *op = res;
}

extern "C" void kernel_launch(void* const* d_in, const int* in_sizes, int n_in,
                              void* d_out, int out_size, void* d_ws, size_t ws_size,
                              hipStream_t stream) {
    const int N = in_sizes[4] / (HH*WW*KK);   // q_depth is (N,H,W,K)
    dim3 grid((WW/TILE) * (HH/TILE) * N);     // flat, 256 tiles per image
    splat_phong<<<grid, dim3(256), 0, stream>>>(
        (const float*)d_in[0],   // texels
        (const float*)d_in[1],   // pixel_normals
        (const float*)d_in[2],   // pixel_coords_cameras
        (const float*)d_in[3],   // pixel_coords_screen
        (const float*)d_in[4],   // q_depth
        (const int*  )d_in[5],   // background_mask
        (const float*)d_in[6],   // light_position
        (const float*)d_in[7],   // light_ambient
        (const float*)d_in[8],   // light_diffuse
        (const float*)d_in[9],   // light_specular
        (const float*)d_in[10],  // camera_position
        (const float*)d_in[11],  // mat_ambient
        (const float*)d_in[12],  // mat_diffuse
        (const float*)d_in[13],  // mat_specular
        (float*)d_out);
}